// Round 1
// baseline (1264.081 us; speedup 1.0000x reference)
//
#include <hip/hip_runtime.h>
#include <cstddef>

#define NN 50000      // nodes
#define NE 800000     // edges (without self loops)
#define NG 250        // graphs
#define TT 200        // nodes per graph / LSTM steps
#define DD 128        // feature dim
#define GH 512        // 4*LSTM_H
#define NEG_SLOPE 0.2f
#define NCHUNK 4
#define CLEN 50       // TT / NCHUNK

static __device__ __forceinline__ float sigm(float x) { return 1.0f / (1.0f + expf(-x)); }

// ------------------------- generic init -------------------------
__global__ void k_seti(int* p, int v, int n) {
    int i = blockIdx.x * 256 + threadIdx.x;
    if (i < n) p[i] = v;
}
__global__ void k_setf(float* p, float v, int n) {
    int i = blockIdx.x * 256 + threadIdx.x;
    if (i < n) p[i] = v;
}

// ------------------------- transpose 128x128 -------------------------
__global__ void k_transpose128(const float* __restrict__ in, float* __restrict__ out) {
    // out[n*128+k] = in[k*128+n]; grid 128 blocks, 128 threads
    int n = blockIdx.x, k = threadIdx.x;
    out[n * DD + k] = in[k * DD + n];
}

// ------------------------- GEMM: C[M,N] = A'[M,128] @ B[N,128]^T (+bias) ---------
// A rows are remapped: flat = (r/clen)*rowsPerGraph + t0 + r%clen  (identity when
// clen==rowsPerGraph, t0==0). B is [N,128] row-major (i.e. already "transposed").
#define LDT 132  // padded LDS row stride in floats (33 float4)
__global__ __launch_bounds__(256) void k_gemm(
    const float* __restrict__ A, const float* __restrict__ B, float* __restrict__ C,
    int M, int N, int t0, int clen, int rowsPerGraph,
    const float* __restrict__ bias1, const float* __restrict__ bias2)
{
    __shared__ float As[128 * LDT];
    __shared__ float Bs[128 * LDT];
    const int tid = threadIdx.x;
    const int m0 = blockIdx.x * 128, n0 = blockIdx.y * 128;

    // load A tile (128 rows x 128 cols), 16 float4 per thread
    #pragma unroll
    for (int it = 0; it < 16; ++it) {
        int f4 = it * 256 + tid;
        int r = f4 >> 5, c4 = f4 & 31;
        int gr = m0 + r;
        float4 v = make_float4(0.f, 0.f, 0.f, 0.f);
        if (gr < M) {
            int flat = (gr / clen) * rowsPerGraph + t0 + (gr % clen);
            v = *(const float4*)(A + (size_t)flat * DD + c4 * 4);
        }
        *(float4*)(As + r * LDT + c4 * 4) = v;
    }
    // load B tile (rows = output cols)
    #pragma unroll
    for (int it = 0; it < 16; ++it) {
        int f4 = it * 256 + tid;
        int r = f4 >> 5, c4 = f4 & 31;
        int gn = n0 + r;
        float4 v = make_float4(0.f, 0.f, 0.f, 0.f);
        if (gn < N) v = *(const float4*)(B + (size_t)gn * DD + c4 * 4);
        *(float4*)(Bs + r * LDT + c4 * 4) = v;
    }
    __syncthreads();

    const int tr = tid >> 4, tc = tid & 15;  // rows tr+i*16, cols tc+j*16 (interleaved)
    float acc[8][8];
    #pragma unroll
    for (int i = 0; i < 8; ++i)
        #pragma unroll
        for (int j = 0; j < 8; ++j) acc[i][j] = 0.f;

    for (int k4 = 0; k4 < 32; ++k4) {
        float4 a[8], b[8];
        #pragma unroll
        for (int i = 0; i < 8; ++i) a[i] = *(const float4*)(As + (tr + i * 16) * LDT + k4 * 4);
        #pragma unroll
        for (int j = 0; j < 8; ++j) b[j] = *(const float4*)(Bs + (tc + j * 16) * LDT + k4 * 4);
        #pragma unroll
        for (int i = 0; i < 8; ++i)
            #pragma unroll
            for (int j = 0; j < 8; ++j)
                acc[i][j] += a[i].x * b[j].x + a[i].y * b[j].y + a[i].z * b[j].z + a[i].w * b[j].w;
    }

    #pragma unroll
    for (int i = 0; i < 8; ++i) {
        int gr = m0 + tr + i * 16;
        if (gr >= M) continue;
        #pragma unroll
        for (int j = 0; j < 8; ++j) {
            int gn = n0 + tc + j * 16;
            if (gn >= N) continue;
            float v = acc[i][j];
            if (bias1) v += bias1[gn];
            if (bias2) v += bias2[gn];
            C[(size_t)gr * N + gn] = v;
        }
    }
}

// ------------------------- alpha_s / alpha_d -------------------------
__global__ __launch_bounds__(256) void k_alpha(
    const float* __restrict__ h1, const float* __restrict__ a_src, const float* __restrict__ a_dst,
    float* __restrict__ as_out, float* __restrict__ ad_out, int n)
{
    int node = blockIdx.x * 4 + (threadIdx.x >> 6);
    int lane = threadIdx.x & 63;
    if (node >= n) return;
    float v0 = h1[(size_t)node * DD + lane];
    float v1 = h1[(size_t)node * DD + 64 + lane];
    float s = v0 * a_src[lane] + v1 * a_src[64 + lane];
    float d = v0 * a_dst[lane] + v1 * a_dst[64 + lane];
    #pragma unroll
    for (int off = 1; off < 64; off <<= 1) {
        s += __shfl_xor(s, off);
        d += __shfl_xor(d, off);
    }
    if (lane == 0) { as_out[node] = s; ad_out[node] = d; }
}

// ------------------------- CSR build -------------------------
__global__ void k_hist(const int* __restrict__ ei, int* cnt, int E) {
    int e = blockIdx.x * 256 + threadIdx.x;
    if (e < E) atomicAdd(&cnt[ei[E + e]], 1);
}

__global__ __launch_bounds__(1024) void k_scan(const int* __restrict__ cnt, int* __restrict__ rp,
                                               int* __restrict__ fill, int n) {
    __shared__ int wsum[16];
    __shared__ int totsh;
    __shared__ int carrysh;
    int lane = threadIdx.x & 63, wid = threadIdx.x >> 6;
    if (threadIdx.x == 0) carrysh = 0;
    __syncthreads();
    for (int base = 0; base < n; base += 4096) {
        int idx = base + threadIdx.x * 4;
        int v0 = (idx < n) ? cnt[idx] : 0;
        int v1 = (idx + 1 < n) ? cnt[idx + 1] : 0;
        int v2 = (idx + 2 < n) ? cnt[idx + 2] : 0;
        int v3 = (idx + 3 < n) ? cnt[idx + 3] : 0;
        int s = v0 + v1 + v2 + v3;
        int sc = s;
        #pragma unroll
        for (int off = 1; off < 64; off <<= 1) {
            int t = __shfl_up(sc, off);
            if (lane >= off) sc += t;
        }
        if (lane == 63) wsum[wid] = sc;
        __syncthreads();
        if (threadIdx.x == 0) {
            int run = 0;
            for (int w = 0; w < 16; ++w) { int t = wsum[w]; wsum[w] = run; run += t; }
            totsh = run;
        }
        __syncthreads();
        int ex = carrysh + wsum[wid] + (sc - s);
        if (idx < n)     { rp[idx] = ex;     fill[idx] = ex; }
        ex += v0;
        if (idx + 1 < n) { rp[idx + 1] = ex; fill[idx + 1] = ex; }
        ex += v1;
        if (idx + 2 < n) { rp[idx + 2] = ex; fill[idx + 2] = ex; }
        ex += v2;
        if (idx + 3 < n) { rp[idx + 3] = ex; fill[idx + 3] = ex; }
        __syncthreads();
        if (threadIdx.x == 0) carrysh += totsh;
        __syncthreads();
    }
    if (threadIdx.x == 0) rp[n] = carrysh;
}

__global__ void k_fill(const int* __restrict__ ei, int* fill, int* esrc, int E, int N) {
    int i = blockIdx.x * 256 + threadIdx.x;
    if (i < E) {
        int s = ei[i], d = ei[E + i];
        int slot = atomicAdd(&fill[d], 1);
        esrc[slot] = s;
    } else if (i < E + N) {
        int v = i - E;
        int slot = atomicAdd(&fill[v], 1);
        esrc[slot] = v;
    }
}

__global__ void k_dinv(const int* __restrict__ rp, float* dinv, int n) {
    int i = blockIdx.x * 256 + threadIdx.x;
    if (i < n) dinv[i] = rsqrtf(fmaxf((float)(rp[i + 1] - rp[i]), 1.0f));
}

// ------------------------- GAT aggregation (wave per node) -------------------------
__global__ __launch_bounds__(256) void k_gat(
    const float* __restrict__ h1, const float* __restrict__ as, const float* __restrict__ ad_,
    const int* __restrict__ rp, const int* __restrict__ esrc,
    const float* __restrict__ bias, float* __restrict__ out, int n)
{
    int node = blockIdx.x * 4 + (threadIdx.x >> 6);
    int lane = threadIdx.x & 63;
    if (node >= n) return;
    int r0 = rp[node], r1 = rp[node + 1];
    float adv = ad_[node];

    float m = -1e30f;
    for (int j = r0 + lane; j < r1; j += 64) {
        float e = as[esrc[j]] + adv;
        e = e > 0.f ? e : NEG_SLOPE * e;
        m = fmaxf(m, e);
    }
    #pragma unroll
    for (int off = 1; off < 64; off <<= 1) m = fmaxf(m, __shfl_xor(m, off));

    float sum = 0.f;
    for (int j = r0 + lane; j < r1; j += 64) {
        float e = as[esrc[j]] + adv;
        e = e > 0.f ? e : NEG_SLOPE * e;
        sum += expf(e - m);
    }
    #pragma unroll
    for (int off = 1; off < 64; off <<= 1) sum += __shfl_xor(sum, off);
    float inv = 1.0f / sum;

    float acc0 = 0.f, acc1 = 0.f;
    for (int j = r0; j < r1; ++j) {
        int s = esrc[j];
        float e = as[s] + adv;
        e = e > 0.f ? e : NEG_SLOPE * e;
        float w = expf(e - m) * inv;
        acc0 += w * h1[(size_t)s * DD + lane];
        acc1 += w * h1[(size_t)s * DD + 64 + lane];
    }
    out[(size_t)node * DD + lane]      = fmaxf(acc0 + bias[lane], 0.f);
    out[(size_t)node * DD + 64 + lane] = fmaxf(acc1 + bias[64 + lane], 0.f);
}

// ------------------------- graph counts -------------------------
__global__ void k_gcount(const int* __restrict__ batch, int* gcount, int n) {
    int i = blockIdx.x * 256 + threadIdx.x;
    if (i < n) atomicAdd(&gcount[batch[i]], 1);
}

// ------------------------- GCN aggregation + scatter to padded ----------------
__global__ __launch_bounds__(256) void k_gcn(
    const float* __restrict__ h2, const float* __restrict__ dinv,
    const int* __restrict__ rp, const int* __restrict__ esrc,
    const float* __restrict__ bias, const int* __restrict__ batch,
    const int* __restrict__ gstart, float* __restrict__ padded, int n)
{
    int node = blockIdx.x * 4 + (threadIdx.x >> 6);
    int lane = threadIdx.x & 63;
    if (node >= n) return;
    int r0 = rp[node], r1 = rp[node + 1];
    float dn = dinv[node];
    float acc0 = 0.f, acc1 = 0.f;
    for (int j = r0; j < r1; ++j) {
        int s = esrc[j];
        float c = dn * dinv[s];
        acc0 += c * h2[(size_t)s * DD + lane];
        acc1 += c * h2[(size_t)s * DD + 64 + lane];
    }
    int g = batch[node];
    if (g < 0 || g >= NG) return;
    int p = node - gstart[g];
    if (p < 0 || p >= TT) return;
    padded[((size_t)g * TT + p) * DD + lane]      = fmaxf(acc0 + bias[lane], 0.f);
    padded[((size_t)g * TT + p) * DD + 64 + lane] = fmaxf(acc1 + bias[64 + lane], 0.f);
}

// ------------------------- LSTM chunk (block per graph) -------------------------
__global__ __launch_bounds__(512) void k_lstm(
    const float* __restrict__ xw,     // [NG*clen, 512] chunk, includes b_ih+b_hh
    const float* __restrict__ Whh,    // [512,128]
    const int* __restrict__ glen,
    float* __restrict__ hstate, float* __restrict__ cstate,
    float* __restrict__ grep, int t0, int clen)
{
    int g = blockIdx.x, tid = threadIdx.x;
    __shared__ __align__(16) float h_sh[DD];
    __shared__ float gates[GH];

    float4 w[32];
    #pragma unroll
    for (int i = 0; i < 32; ++i) w[i] = *(const float4*)(Whh + (size_t)tid * DD + i * 4);

    float creg = 0.f;
    if (t0 == 0) {
        if (tid < DD) h_sh[tid] = 0.f;
    } else {
        if (tid < DD) { h_sh[tid] = hstate[g * DD + tid]; creg = cstate[g * DD + tid]; }
    }
    int len = glen[g];
    int take = len - 1;
    if (take < 0) take = 0;
    if (take > TT - 1) take = TT - 1;
    __syncthreads();

    for (int t = t0; t < t0 + clen; ++t) {
        float gate = xw[((size_t)g * clen + (t - t0)) * GH + tid];
        #pragma unroll
        for (int i = 0; i < 32; ++i) {
            float4 hv = *(const float4*)(h_sh + i * 4);
            gate += hv.x * w[i].x + hv.y * w[i].y + hv.z * w[i].z + hv.w * w[i].w;
        }
        gates[tid] = gate;
        __syncthreads();
        if (tid < DD) {
            float gi = gates[tid], gf = gates[DD + tid], gg = gates[2 * DD + tid], go = gates[3 * DD + tid];
            creg = sigm(gf) * creg + sigm(gi) * tanhf(gg);
            float hn = sigm(go) * tanhf(creg);
            h_sh[tid] = hn;
            if (t == take) grep[g * DD + tid] = hn;
        }
        __syncthreads();
    }
    if (tid < DD) { hstate[g * DD + tid] = h_sh[tid]; cstate[g * DD + tid] = creg; }
}

// ------------------------- FC -------------------------
__global__ void k_fc(const float* __restrict__ grep, const float* __restrict__ Wfc,
                     const float* __restrict__ bfc, float* __restrict__ out, int G) {
    int i = blockIdx.x * 256 + threadIdx.x;
    if (i >= G * 2) return;
    int g = i >> 1, o = i & 1;
    float acc = bfc[o];
    for (int d = 0; d < DD; ++d) acc += grep[g * DD + d] * Wfc[d * 2 + o];
    out[i] = acc;
}

// ------------------------- host launch -------------------------
extern "C" void kernel_launch(void* const* d_in, const int* in_sizes, int n_in,
                              void* d_out, int out_size, void* d_ws, size_t ws_size,
                              hipStream_t stream) {
    const float* x     = (const float*)d_in[0];
    const int*   ei    = (const int*)d_in[1];
    const int*   batch = (const int*)d_in[2];
    const float* Wgat  = (const float*)d_in[3];
    const float* a_src = (const float*)d_in[4];
    const float* a_dst = (const float*)d_in[5];
    const float* b_gat = (const float*)d_in[6];
    const float* Wgcn  = (const float*)d_in[7];
    const float* b_gcn = (const float*)d_in[8];
    const float* Wih   = (const float*)d_in[9];   // [512,128]
    const float* Whh   = (const float*)d_in[10];  // [512,128]
    const float* b_ih  = (const float*)d_in[11];
    const float* b_hh  = (const float*)d_in[12];
    const float* Wfc   = (const float*)d_in[13];
    const float* b_fc  = (const float*)d_in[14];
    float* out = (float*)d_out;

    float* ws = (float*)d_ws;
    const size_t F = (size_t)NN * DD;  // 6.4M floats
    // Region 0: h1 -> h2 -> xw chunk (all dead before successor is written)
    float* h1 = ws;
    float* h2 = ws;
    float* xw = ws;
    // Region B: gat_out -> padded
    float* gato   = ws + F;
    float* padded = ws + F;
    // small region
    size_t off = 2 * F;
    float* alpha_s = ws + off; off += 50048;
    float* alpha_d = ws + off; off += 50048;
    float* dinv    = ws + off; off += 50048;
    int*   cnt     = (int*)(ws + off); off += 50048;
    int*   rp      = (int*)(ws + off); off += 50056;
    int*   fill    = (int*)(ws + off); off += 50048;
    int*   esrc    = (int*)(ws + off); off += 850048;
    int*   gcount  = (int*)(ws + off); off += 256;
    int*   gstart  = (int*)(ws + off); off += 256;
    int*   gfill   = (int*)(ws + off); off += 256;
    float* grep    = ws + off; off += 32000;
    float* hstate  = ws + off; off += 32000;
    float* cstate  = ws + off; off += 32000;
    float* WgatT   = ws + off; off += 16384;
    float* WgcnT   = ws + off; off += 16384;

    // 1. transpose weights to [N,K]
    k_transpose128<<<128, 128, 0, stream>>>(Wgat, WgatT);
    k_transpose128<<<128, 128, 0, stream>>>(Wgcn, WgcnT);

    // 2. h1 = x @ W_gat
    k_gemm<<<dim3(391, 1), 256, 0, stream>>>(x, WgatT, h1, NN, DD, 0, TT, TT, nullptr, nullptr);

    // 3. alpha
    k_alpha<<<12500, 256, 0, stream>>>(h1, a_src, a_dst, alpha_s, alpha_d, NN);

    // 4. CSR build (counts start at 1 for self loop)
    k_seti<<<196, 256, 0, stream>>>(cnt, 1, NN);
    k_seti<<<1, 256, 0, stream>>>(gcount, 0, 256);
    k_hist<<<3125, 256, 0, stream>>>(ei, cnt, NE);
    k_scan<<<1, 1024, 0, stream>>>(cnt, rp, fill, NN);
    k_fill<<<3321, 256, 0, stream>>>(ei, fill, esrc, NE, NN);
    k_dinv<<<196, 256, 0, stream>>>(rp, dinv, NN);

    // 5. GAT aggregation -> gato (relu + bias fused)
    k_gat<<<12500, 256, 0, stream>>>(h1, alpha_s, alpha_d, rp, esrc, b_gat, gato, NN);

    // 6. h2 = gato @ W_gcn   (overwrites h1, which is dead)
    k_gemm<<<dim3(391, 1), 256, 0, stream>>>(gato, WgcnT, h2, NN, DD, 0, TT, TT, nullptr, nullptr);

    // 7. batch bookkeeping
    k_gcount<<<196, 256, 0, stream>>>(batch, gcount, NN);
    k_scan<<<1, 1024, 0, stream>>>(gcount, gstart, gfill, NG);

    // 8. zero padded (overwrites gato, which is dead), then GCN aggregation -> padded
    k_setf<<<25000, 256, 0, stream>>>(padded, 0.f, (int)F);
    k_gcn<<<12500, 256, 0, stream>>>(h2, dinv, rp, esrc, b_gcn, batch, gstart, padded, NN);

    // 9. LSTM in NCHUNK time chunks: xw = padded_chunk @ W_ih^T + b_ih + b_hh, then recur
    for (int c = 0; c < NCHUNK; ++c) {
        int t0 = c * CLEN;
        k_gemm<<<dim3(98, 4), 256, 0, stream>>>(padded, Wih, xw, NG * CLEN, GH,
                                                t0, CLEN, TT, b_ih, b_hh);
        k_lstm<<<NG, 512, 0, stream>>>(xw, Whh, gcount, hstate, cstate, grep, t0, CLEN);
    }

    // 10. FC
    k_fc<<<2, 256, 0, stream>>>(grep, Wfc, b_fc, out, NG);
}